// Round 5
// baseline (366.318 us; speedup 1.0000x reference)
//
#include <hip/hip_runtime.h>
#include <hip/hip_bf16.h>

#define NNODES 20000
#define EEDGES 320000
#define FIN 1024
#define HMID 256
#define DOUT 128
#define ALPHA_BLOCKS ((NNODES + 3) / 4)

typedef __bf16 bf16x8 __attribute__((ext_vector_type(8)));
typedef __bf16 bf16x4 __attribute__((ext_vector_type(4)));
typedef __bf16 bf16x2 __attribute__((ext_vector_type(2)));
typedef float f32x4 __attribute__((ext_vector_type(4)));

// ---------------- weight packing ----------------
// Wtp: for 32-k block kk (0..31), col-half h (128 cols): 512 16B-units; unit u = kq*128 + (col&127)
// holds W_gcn[kk*32+kq*8+j][col], j in 0..8. Elem addr: ((kk*2+h)*512 + u)*8 + j.
// A B-fragment read (16 lanes m=0..15, fixed q,jb) is 256B contiguous.
__global__ void k_pack_w(const float* __restrict__ W, __bf16* __restrict__ Wtp) {
    int tid = blockIdx.x * 256 + threadIdx.x;
    if (tid >= FIN * HMID) return;
    int k = tid >> 8;
    int n = tid & 255;
    int kk = k >> 5, kq = (k >> 3) & 3, j = k & 7;
    int h = n >> 7;
    int u = kq * 128 + (n & 127);
    Wtp[((size_t)(kk * 2 + h) * 512 + u) * 8 + j] = (__bf16)W[tid];
}

__global__ void k_prep_watt(const float* __restrict__ Wq, const float* __restrict__ Wk,
                            const float* __restrict__ Wv, const float* __restrict__ Ws,
                            const float* __restrict__ bq, const float* __restrict__ bk,
                            const float* __restrict__ bv, const float* __restrict__ bs,
                            __bf16* __restrict__ Wallt, float* __restrict__ ball) {
    int g = blockIdx.y;
    const float* W = (g == 0) ? Wq : (g == 1) ? Wk : (g == 2) ? Wv : Ws;
    int tid = blockIdx.x * 256 + threadIdx.x;
    if (tid < HMID * DOUT) {
        int k = tid >> 7;
        int n = tid & 127;
        Wallt[(size_t)(g * DOUT + n) * HMID + k] = (__bf16)W[tid];
    }
    if (tid < DOUT) {
        const float* b = (g == 0) ? bq : (g == 1) ? bk : (g == 2) ? bv : bs;
        ball[g * DOUT + tid] = b[tid];
    }
}

// ---------------- CSR build ----------------
__global__ void k_init(int* __restrict__ cnt, float* __restrict__ S) {
    int i = blockIdx.x * 256 + threadIdx.x;
    if (i < NNODES) cnt[i] = 0;
    if (i < 16) S[i] = 0.0f;
}

__global__ void k_count(const int* __restrict__ dst, int* __restrict__ cnt) {
    int e = blockIdx.x * 256 + threadIdx.x;
    if (e < EEDGES) atomicAdd(&cnt[dst[e]], 1);
}

__global__ void k_dinv(const int* __restrict__ cnt, float* __restrict__ dinv,
                       int* __restrict__ cursor) {
    int i = blockIdx.x * 256 + threadIdx.x;
    if (i < NNODES) {
        dinv[i] = rsqrtf((float)cnt[i] + 1.0f);
        cursor[i] = 0;
    }
}

__global__ __launch_bounds__(1024) void k_scan(const int* __restrict__ cnt,
                                               int* __restrict__ rowptr) {
    __shared__ int sh[1024];
    int t = threadIdx.x;
    int base = t * 20;
    int local[20];
    int sum = 0;
#pragma unroll
    for (int j = 0; j < 20; j++) {
        int i = base + j;
        int v = (i < NNODES) ? cnt[i] : 0;
        local[j] = sum;
        sum += v;
    }
    sh[t] = sum;
    __syncthreads();
    for (int off = 1; off < 1024; off <<= 1) {
        int v = (t >= off) ? sh[t - off] : 0;
        __syncthreads();
        sh[t] += v;
        __syncthreads();
    }
    int prev = (t > 0) ? sh[t - 1] : 0;
#pragma unroll
    for (int j = 0; j < 20; j++) {
        int i = base + j;
        if (i < NNODES) rowptr[i] = prev + local[j];
    }
    if (t == 1023) rowptr[NNODES] = sh[1023];
}

__global__ void k_fill(const int* __restrict__ src, const int* __restrict__ dst,
                       const int* __restrict__ rowptr, int* __restrict__ cursor,
                       const float* __restrict__ dinv,
                       int* __restrict__ srcsorted, float* __restrict__ wsorted) {
    int e = blockIdx.x * 256 + threadIdx.x;
    if (e >= EEDGES) return;
    int d = dst[e];
    int s = src[e];
    int pos = atomicAdd(&cursor[d], 1);
    int w = rowptr[d] + pos;
    srcsorted[w] = s;
    wsorted[w] = dinv[s];
}

// ---------------- GEMM1: h0bf = bf16(x @ W_gcn) ----------------
// BARRIER-FREE / LDS-FREE: r0-r4 all plateaued 49-60us regardless of occupancy --
// the block-wide barrier convoy per K-step was the invariant. Here every lane reads
// its MFMA fragments directly from global (A: 16 rows x 128B contiguous chunks from x,
// L1/L2-served 4-wave reuse; B: 256B contiguous from L2-resident packed Wtp), register
// ping/pong double-buffer (named sets, rule #20), zero syncthreads. Waves slip freely;
// TLP hides latency without convoy amplification.
// 32x128 tile, grid (625,2); fragment mapping identical to the r1-verified kernel:
// A[row=i*16+m][k=kk*32+q*8+j], B[k][col=wc+jb*16+m], C[r0+i*16+q*4+r][c0+wc+jb*16+m].
#define G1_LOAD(A0L, A0H, A1L, A1H, B0, B1, KK) do {                          \
    const float* _a0 = a0p + (KK) * 32;                                       \
    const float* _a1 = a1p + (KK) * 32;                                       \
    A0L = *(const float4*)_a0;  A0H = *(const float4*)(_a0 + 4);              \
    A1L = *(const float4*)_a1;  A1H = *(const float4*)(_a1 + 4);              \
    const __bf16* _b = bp + (size_t)(KK) * 8192;                              \
    B0 = *(const bf16x8*)_b;  B1 = *(const bf16x8*)(_b + 128);                \
} while (0)

#define G1_COMP(A0L, A0H, A1L, A1H, B0, B1) do {                              \
    bf16x8 _af0, _af1;                                                        \
    _af0[0] = (__bf16)A0L.x; _af0[1] = (__bf16)A0L.y;                         \
    _af0[2] = (__bf16)A0L.z; _af0[3] = (__bf16)A0L.w;                         \
    _af0[4] = (__bf16)A0H.x; _af0[5] = (__bf16)A0H.y;                         \
    _af0[6] = (__bf16)A0H.z; _af0[7] = (__bf16)A0H.w;                         \
    _af1[0] = (__bf16)A1L.x; _af1[1] = (__bf16)A1L.y;                         \
    _af1[2] = (__bf16)A1L.z; _af1[3] = (__bf16)A1L.w;                         \
    _af1[4] = (__bf16)A1H.x; _af1[5] = (__bf16)A1H.y;                         \
    _af1[6] = (__bf16)A1H.z; _af1[7] = (__bf16)A1H.w;                         \
    acc[0][0] = __builtin_amdgcn_mfma_f32_16x16x32_bf16(_af0, B0, acc[0][0], 0, 0, 0); \
    acc[0][1] = __builtin_amdgcn_mfma_f32_16x16x32_bf16(_af0, B1, acc[0][1], 0, 0, 0); \
    acc[1][0] = __builtin_amdgcn_mfma_f32_16x16x32_bf16(_af1, B0, acc[1][0], 0, 0, 0); \
    acc[1][1] = __builtin_amdgcn_mfma_f32_16x16x32_bf16(_af1, B1, acc[1][1], 0, 0, 0); \
} while (0)

__global__ __launch_bounds__(256, 3) void k_gemm1(const float* __restrict__ x,
                                                  const __bf16* __restrict__ Wtp,
                                                  __bf16* __restrict__ h0bf) {
    int t = threadIdx.x;
    int lane = t & 63;
    int m = lane & 15, q = lane >> 4;
    int w = t >> 6;
    int wc = w * 32;              // wave owns 32 cols, all 32 rows
    int r0 = blockIdx.x * 32;
    int h = blockIdx.y;
    int c0 = h * 128;

    const float* a0p = x + (size_t)(r0 + m) * FIN + q * 8;        // i=0 rows
    const float* a1p = x + (size_t)(r0 + 16 + m) * FIN + q * 8;   // i=1 rows
    const __bf16* bp = Wtp + ((size_t)h * 512 + q * 128 + wc + m) * 8;

    f32x4 acc[2][2] = {};

    float4 pa0l, pa0h, pa1l, pa1h;  bf16x8 pb0, pb1;   // ping
    float4 qa0l, qa0h, qa1l, qa1h;  bf16x8 qb0, qb1;   // pong

    G1_LOAD(pa0l, pa0h, pa1l, pa1h, pb0, pb1, 0);

#pragma unroll 1
    for (int kk = 0; kk < 32; kk += 2) {
        G1_LOAD(qa0l, qa0h, qa1l, qa1h, qb0, qb1, kk + 1);
        G1_COMP(pa0l, pa0h, pa1l, pa1h, pb0, pb1);
        int kn = (kk + 2 < 32) ? kk + 2 : 30;   // clamped redundant reload at tail
        G1_LOAD(pa0l, pa0h, pa1l, pa1h, pb0, pb1, kn);
        G1_COMP(qa0l, qa0h, qa1l, qa1h, qb0, qb1);
    }

#pragma unroll
    for (int i = 0; i < 2; i++)
#pragma unroll
        for (int jb = 0; jb < 2; jb++)
#pragma unroll
            for (int r = 0; r < 4; r++) {
                int row = r0 + i * 16 + q * 4 + r;
                int col = c0 + wc + jb * 16 + m;
                h0bf[(size_t)row * 256 + col] = (__bf16)acc[i][jb][r];
            }
}

// ---------------- GCN gather (batch-4 MLP) ----------------
__global__ __launch_bounds__(256) void k_gcn_gather(const int* __restrict__ rowptr,
                                                    const int* __restrict__ srcsorted,
                                                    const float* __restrict__ wsorted,
                                                    const __bf16* __restrict__ h0bf,
                                                    const float* __restrict__ dinv,
                                                    const float* __restrict__ bgcn,
                                                    __bf16* __restrict__ hbf) {
    int gid = blockIdx.x * 256 + threadIdx.x;
    int n = gid >> 6, l = gid & 63;
    if (n >= NNODES) return;
    float dn = dinv[n];
    float wn = dn * dn;
    bf16x4 hv = *(const bf16x4*)(h0bf + (size_t)n * 256 + l * 4);
    float4 b = ((const float4*)bgcn)[l];
    float ax = (float)hv[0] * wn + b.x;
    float ay = (float)hv[1] * wn + b.y;
    float az = (float)hv[2] * wn + b.z;
    float aw = (float)hv[3] * wn + b.w;
    int beg = rowptr[n], end = rowptr[n + 1];
    for (int i = beg; i < end; i += 4) {
        int i1 = i + 1 < end ? i + 1 : end - 1;
        int i2 = i + 2 < end ? i + 2 : end - 1;
        int i3 = i + 3 < end ? i + 3 : end - 1;
        int s0 = srcsorted[i], s1 = srcsorted[i1], s2 = srcsorted[i2], s3 = srcsorted[i3];
        float w0 = wsorted[i] * dn;
        float w1 = (i + 1 < end) ? wsorted[i1] * dn : 0.f;
        float w2 = (i + 2 < end) ? wsorted[i2] * dn : 0.f;
        float w3 = (i + 3 < end) ? wsorted[i3] * dn : 0.f;
        bf16x4 v0 = *(const bf16x4*)(h0bf + (size_t)s0 * 256 + l * 4);
        bf16x4 v1 = *(const bf16x4*)(h0bf + (size_t)s1 * 256 + l * 4);
        bf16x4 v2 = *(const bf16x4*)(h0bf + (size_t)s2 * 256 + l * 4);
        bf16x4 v3 = *(const bf16x4*)(h0bf + (size_t)s3 * 256 + l * 4);
        ax += (float)v0[0] * w0 + (float)v1[0] * w1 + (float)v2[0] * w2 + (float)v3[0] * w3;
        ay += (float)v0[1] * w0 + (float)v1[1] * w1 + (float)v2[1] * w2 + (float)v3[1] * w3;
        az += (float)v0[2] * w0 + (float)v1[2] * w1 + (float)v2[2] * w2 + (float)v3[2] * w3;
        aw += (float)v0[3] * w0 + (float)v1[3] * w1 + (float)v2[3] * w2 + (float)v3[3] * w3;
    }
    bf16x4 o;
    o[0] = (__bf16)(ax >= 0.f ? ax : 0.01f * ax);
    o[1] = (__bf16)(ay >= 0.f ? ay : 0.01f * ay);
    o[2] = (__bf16)(az >= 0.f ? az : 0.01f * az);
    o[3] = (__bf16)(aw >= 0.f ? aw : 0.01f * aw);
    *(bf16x4*)(hbf + (size_t)n * 256 + l * 4) = o;
}

// ---------------- GEMM2 (barrier-free, LDS-free, same mechanism as gemm1) ----------------
// 128x128 tile, 4 waves x (64x64), K=256, BK=32 -> 8 steps as 4 ping/pong pairs.
// A frags: 4 q-lanes x 16B = 64B contiguous per hbf row; B same from Wallt (L2-hot).
#define G2_LOAD(PA, PB, K0) do {                                              \
    PA##0 = *(const bf16x8*)(ap0 + (K0));                                     \
    PA##1 = *(const bf16x8*)(ap1 + (K0));                                     \
    PA##2 = *(const bf16x8*)(ap2 + (K0));                                     \
    PA##3 = *(const bf16x8*)(ap3 + (K0));                                     \
    PB##0 = *(const bf16x8*)(bp0 + (K0));                                     \
    PB##1 = *(const bf16x8*)(bp1 + (K0));                                     \
    PB##2 = *(const bf16x8*)(bp2 + (K0));                                     \
    PB##3 = *(const bf16x8*)(bp3 + (K0));                                     \
} while (0)

#define G2_COMP(PA, PB) do {                                                  \
    acc[0][0] = __builtin_amdgcn_mfma_f32_16x16x32_bf16(PA##0, PB##0, acc[0][0], 0, 0, 0); \
    acc[0][1] = __builtin_amdgcn_mfma_f32_16x16x32_bf16(PA##0, PB##1, acc[0][1], 0, 0, 0); \
    acc[0][2] = __builtin_amdgcn_mfma_f32_16x16x32_bf16(PA##0, PB##2, acc[0][2], 0, 0, 0); \
    acc[0][3] = __builtin_amdgcn_mfma_f32_16x16x32_bf16(PA##0, PB##3, acc[0][3], 0, 0, 0); \
    acc[1][0] = __builtin_amdgcn_mfma_f32_16x16x32_bf16(PA##1, PB##0, acc[1][0], 0, 0, 0); \
    acc[1][1] = __builtin_amdgcn_mfma_f32_16x16x32_bf16(PA##1, PB##1, acc[1][1], 0, 0, 0); \
    acc[1][2] = __builtin_amdgcn_mfma_f32_16x16x32_bf16(PA##1, PB##2, acc[1][2], 0, 0, 0); \
    acc[1][3] = __builtin_amdgcn_mfma_f32_16x16x32_bf16(PA##1, PB##3, acc[1][3], 0, 0, 0); \
    acc[2][0] = __builtin_amdgcn_mfma_f32_16x16x32_bf16(PA##2, PB##0, acc[2][0], 0, 0, 0); \
    acc[2][1] = __builtin_amdgcn_mfma_f32_16x16x32_bf16(PA##2, PB##1, acc[2][1], 0, 0, 0); \
    acc[2][2] = __builtin_amdgcn_mfma_f32_16x16x32_bf16(PA##2, PB##2, acc[2][2], 0, 0, 0); \
    acc[2][3] = __builtin_amdgcn_mfma_f32_16x16x32_bf16(PA##2, PB##3, acc[2][3], 0, 0, 0); \
    acc[3][0] = __builtin_amdgcn_mfma_f32_16x16x32_bf16(PA##3, PB##0, acc[3][0], 0, 0, 0); \
    acc[3][1] = __builtin_amdgcn_mfma_f32_16x16x32_bf16(PA##3, PB##1, acc[3][1], 0, 0, 0); \
    acc[3][2] = __builtin_amdgcn_mfma_f32_16x16x32_bf16(PA##3, PB##2, acc[3][2], 0, 0, 0); \
    acc[3][3] = __builtin_amdgcn_mfma_f32_16x16x32_bf16(PA##3, PB##3, acc[3][3], 0, 0, 0); \
} while (0)

__global__ __launch_bounds__(256, 2) void k_gemm2(const __bf16* __restrict__ hbf,
                                                  const __bf16* __restrict__ Wallt,
                                                  const float* __restrict__ ball,
                                                  __bf16* __restrict__ qarr,
                                                  __bf16* __restrict__ karr,
                                                  __bf16* __restrict__ varr,
                                                  __bf16* __restrict__ sarr) {
    int t = threadIdx.x;
    int lane = t & 63;
    int m = lane & 15, q = lane >> 4;
    int wave = t >> 6;
    int wr = (wave & 1) * 64;
    int wc = (wave >> 1) * 64;
    int r0 = blockIdx.x * 128;
    int c0 = blockIdx.y * 128;
    __bf16* tbl = (blockIdx.y == 0) ? qarr : (blockIdx.y == 1) ? karr
                : (blockIdx.y == 2) ? varr : sarr;

    int rows[4];
#pragma unroll
    for (int i = 0; i < 4; i++) {
        int row = r0 + wr + i * 16 + m;
        rows[i] = (row < NNODES) ? row : NNODES - 1;
    }
    const __bf16* ap0 = hbf + (size_t)rows[0] * HMID + q * 8;
    const __bf16* ap1 = hbf + (size_t)rows[1] * HMID + q * 8;
    const __bf16* ap2 = hbf + (size_t)rows[2] * HMID + q * 8;
    const __bf16* ap3 = hbf + (size_t)rows[3] * HMID + q * 8;
    const __bf16* bp0 = Wallt + (size_t)(c0 + wc +  0 + m) * HMID + q * 8;
    const __bf16* bp1 = Wallt + (size_t)(c0 + wc + 16 + m) * HMID + q * 8;
    const __bf16* bp2 = Wallt + (size_t)(c0 + wc + 32 + m) * HMID + q * 8;
    const __bf16* bp3 = Wallt + (size_t)(c0 + wc + 48 + m) * HMID + q * 8;

    f32x4 acc[4][4] = {};

    bf16x8 pa0, pa1, pa2, pa3, pb0, pb1, pb2, pb3;   // ping
    bf16x8 qa0, qa1, qa2, qa3, qb0, qb1, qb2, qb3;   // pong

    G2_LOAD(pa, pb, 0);

#pragma unroll 1
    for (int k0 = 0; k0 < HMID; k0 += 64) {
        G2_LOAD(qa, qb, k0 + 32);
        G2_COMP(pa, pb);
        int kn = (k0 + 64 < HMID) ? k0 + 64 : HMID - 64;  // clamped tail reload
        G2_LOAD(pa, pb, kn);
        G2_COMP(qa, qb);
    }

#pragma unroll
    for (int jb = 0; jb < 4; jb++) {
        int dcol = wc + jb * 16 + m;
        float bias = ball[c0 + dcol];
#pragma unroll
        for (int i = 0; i < 4; i++)
#pragma unroll
            for (int r = 0; r < 4; r++) {
                int row = r0 + wr + i * 16 + q * 4 + r;
                if (row < NNODES) tbl[(size_t)row * 128 + dcol] = (__bf16)(acc[i][jb][r] + bias);
            }
    }
}

// ---------------- attention scores ----------------
__global__ __launch_bounds__(256) void k_alpha(const int* __restrict__ rowptr,
                                               const int* __restrict__ srcsorted,
                                               const __bf16* __restrict__ qarr,
                                               const __bf16* __restrict__ karr,
                                               float* __restrict__ alpha,
                                               float* __restrict__ part) {
    int n = (blockIdx.x * 256 + threadIdx.x) >> 6;
    int lane = threadIdx.x & 63;
    int g = lane >> 4, l = lane & 15;
    float s1 = 0.f, s2 = 0.f;
    if (n < NNODES) {
        bf16x8 qb = *(const bf16x8*)(qarr + (size_t)n * 128 + l * 8);
        float qf[8];
#pragma unroll
        for (int j = 0; j < 8; j++) qf[j] = (float)qb[j];
        int beg = rowptr[n], end = rowptr[n + 1];
        for (int i = beg + g; i < end; i += 16) {
            int i1 = i + 4 < end ? i + 4 : end - 1;
            int i2 = i + 8 < end ? i + 8 : end - 1;
            int i3 = i + 12 < end ? i + 12 : end - 1;
            int s0 = srcsorted[i], sA = srcsorted[i1], sB = srcsorted[i2], sC = srcsorted[i3];
            bf16x8 k0 = *(const bf16x8*)(karr + (size_t)s0 * 128 + l * 8);
            bf16x8 k1 = *(const bf16x8*)(karr + (size_t)sA * 128 + l * 8);
            bf16x8 k2 = *(const bf16x8*)(karr + (size_t)sB * 128 + l * 8);
            bf16x8 k3 = *(const bf16x8*)(karr + (size_t)sC * 128 + l * 8);
            float d0 = 0.f, d1 = 0.f, d2 = 0.f, d3 = 0.f;
#pragma unroll
            for (int j = 0; j < 8; j++) {
                d0 += qf[j] * (float)k0[j];
                d1 += qf[j] * (float)k1[j];
                d2 += qf[j] * (float)k2[j];
                d3 += qf[j] * (float)k3[j];
            }
#pragma unroll
            for (int off = 1; off < 16; off <<= 1) {
                d0 += __shfl_xor(d0, off, 64);
                d1 += __shfl_xor(d1, off, 64);
                d2 += __shfl_xor(d2, off, 64);
                d3 += __shfl_xor(d3, off, 64);
            }
            if (l == 0) {
                const float sc = 0.08838834764831845f;
                float a0 = d0 * sc;
                alpha[i] = a0; s1 += a0; s2 += a0 * a0;
                if (i + 4 < end)  { float a = d1 * sc; alpha[i + 4]  = a; s1 += a; s2 += a * a; }
                if (i + 8 < end)  { float a = d2 * sc; alpha[i + 8]  = a; s1 += a; s2 += a * a; }
                if (i + 12 < end) { float a = d3 * sc; alpha[i + 12] = a; s1 += a; s2 += a * a; }
            }
        }
    }
#pragma unroll
    for (int off = 1; off < 64; off <<= 1) {
        s1 += __shfl_xor(s1, off, 64);
        s2 += __shfl_xor(s2, off, 64);
    }
    __shared__ float sh[8];
    int wave = threadIdx.x >> 6;
    if ((threadIdx.x & 63) == 0) { sh[wave] = s1; sh[4 + wave] = s2; }
    __syncthreads();
    if (threadIdx.x == 0) {
        part[2 * blockIdx.x]     = sh[0] + sh[1] + sh[2] + sh[3];
        part[2 * blockIdx.x + 1] = sh[4] + sh[5] + sh[6] + sh[7];
    }
}

__global__ __launch_bounds__(1024) void k_stats(const float* __restrict__ part,
                                                float* __restrict__ S) {
    float s1 = 0.f, s2 = 0.f;
    for (int i = threadIdx.x; i < ALPHA_BLOCKS; i += 1024) {
        s1 += part[2 * i];
        s2 += part[2 * i + 1];
    }
#pragma unroll
    for (int off = 1; off < 64; off <<= 1) {
        s1 += __shfl_xor(s1, off, 64);
        s2 += __shfl_xor(s2, off, 64);
    }
    __shared__ float sh1[16], sh2[16];
    int wave = threadIdx.x >> 6;
    if ((threadIdx.x & 63) == 0) { sh1[wave] = s1; sh2[wave] = s2; }
    __syncthreads();
    if (threadIdx.x == 0) {
        float t1 = 0.f, t2 = 0.f;
#pragma unroll
        for (int w = 0; w < 16; w++) { t1 += sh1[w]; t2 += sh2[w]; }
        float mean = t1 / (float)EEDGES;
        float var = (t2 - (float)EEDGES * mean * mean) / (float)(EEDGES - 1);
        float stdv = sqrtf(fmaxf(var, 1e-20f));
        S[2] = mean;
        S[3] = 3.0f / stdv;
    }
}

// ---------------- output gather ----------------
__global__ __launch_bounds__(256) void k_msg_gather(const int* __restrict__ rowptr,
                                                    const int* __restrict__ srcsorted,
                                                    const __bf16* __restrict__ varr,
                                                    const __bf16* __restrict__ sarr,
                                                    const float* __restrict__ alpha,
                                                    const float* __restrict__ S,
                                                    float* __restrict__ out) {
    int n = (blockIdx.x * 256 + threadIdx.x) >> 6;
    int l = threadIdx.x & 63;
    if (n >= NNODES) return;
    float mean = S[2], scl = S[3];
    bf16x2 sb = *(const bf16x2*)(sarr + (size_t)n * 128 + l * 2);
    float ax = (float)sb[0], ay = (float)sb[1];
    int beg = rowptr[n], end = rowptr[n + 1];
    for (int i = beg; i < end; i += 4) {
        int i1 = i + 1 < end ? i + 1 : end - 1;
        int i2 = i + 2 < end ? i + 2 : end - 1;
        int i3 = i + 3 < end ? i + 3 : end - 1;
        int s0 = srcsorted[i], s1 = srcsorted[i1], s2 = srcsorted[i2], s3 = srcsorted[i3];
        float z0 = (alpha[i] - mean) * scl;
        float z1 = (alpha[i1] - mean) * scl;
        float z2 = (alpha[i2] - mean) * scl;
        float z3 = (alpha[i3] - mean) * scl;
        float g0 = 1.0f / (1.0f + __expf(-z0));
        float g1 = (i + 1 < end) ? 1.0f / (1.0f + __expf(-z1)) : 0.f;
        float g2 = (i + 2 < end) ? 1.0f / (1.0f + __expf(-z2)) : 0.f;
        float g3 = (i + 3 < end) ? 1.0f / (1.0f + __expf(-z3)) : 0.f;
        bf16x2 v0 = *(const bf16x2*)(varr + (size_t)s0 * 128 + l * 2);
        bf16x2 v1 = *(const bf16x2*)(varr + (size_t)s1 * 128 + l * 2);
        bf16x2 v2 = *(const bf16x2*)(varr + (size_t)s2 * 128 + l * 2);
        bf16x2 v3 = *(const bf16x2*)(varr + (size_t)s3 * 128 + l * 2);
        ax += (float)v0[0] * g0 + (float)v1[0] * g1 + (float)v2[0] * g2 + (float)v3[0] * g3;
        ay += (float)v0[1] * g0 + (float)v1[1] * g1 + (float)v2[1] * g2 + (float)v3[1] * g3;
    }
    float2 o; o.x = ax; o.y = ay;
    ((float2*)(out + (size_t)n * DOUT))[l] = o;
}

// ---------------- launch ----------------
extern "C" void kernel_launch(void* const* d_in, const int* in_sizes, int n_in,
                              void* d_out, int out_size, void* d_ws, size_t ws_size,
                              hipStream_t stream) {
    const float* x  = (const float*)d_in[0];
    const int* ei   = (const int*)d_in[1];
    const int* srcI = ei;
    const int* dstI = ei + EEDGES;
    const float* Wg = (const float*)d_in[2];
    const float* bg = (const float*)d_in[3];
    const float* Wq = (const float*)d_in[4];  const float* bq = (const float*)d_in[5];
    const float* Wk = (const float*)d_in[6];  const float* bk = (const float*)d_in[7];
    const float* Wv = (const float*)d_in[8];  const float* bv = (const float*)d_in[9];
    const float* Ws = (const float*)d_in[10]; const float* bs = (const float*)d_in[11];
    float* out = (float*)d_out;

    char* wsb = (char*)d_ws;
    size_t off = 0;
    auto alloc = [&](size_t bytes) -> void* {
        void* p = wsb + off;
        off += (bytes + 255) & ~(size_t)255;
        return p;
    };
    int*    cnt    = (int*)alloc((size_t)NNODES * 4);
    int*    rowptr = (int*)alloc((size_t)(NNODES + 1) * 4);
    int*    cursor = (int*)alloc((size_t)NNODES * 4);
    int*    srcst  = (int*)alloc((size_t)EEDGES * 4);
    float*  wsort  = (float*)alloc((size_t)EEDGES * 4);
    float*  dinv   = (float*)alloc((size_t)NNODES * 4);
    float*  S      = (float*)alloc(64);
    float*  part   = (float*)alloc((size_t)ALPHA_BLOCKS * 2 * 4);
    __bf16* Wtp    = (__bf16*)alloc((size_t)32 * 8192 * 2);
    __bf16* Wallt  = (__bf16*)alloc((size_t)512 * HMID * 2);
    float*  ball   = (float*)alloc(512 * 4);
    __bf16* h0bf   = (__bf16*)alloc((size_t)NNODES * HMID * 2);
    __bf16* hbf    = (__bf16*)alloc((size_t)NNODES * HMID * 2);
    __bf16* qarr   = (__bf16*)alloc((size_t)NNODES * 128 * 2);
    __bf16* karr   = (__bf16*)alloc((size_t)NNODES * 128 * 2);
    __bf16* varr   = (__bf16*)alloc((size_t)NNODES * 128 * 2);
    __bf16* sarr   = (__bf16*)alloc((size_t)NNODES * 128 * 2);
    float*  alphab = (float*)alloc((size_t)EEDGES * 4);
    if (off > ws_size) return;

    k_pack_w<<<(FIN * HMID + 255) / 256, 256, 0, stream>>>(Wg, Wtp);
    dim3 gw((HMID * DOUT + 255) / 256, 4);
    k_prep_watt<<<gw, 256, 0, stream>>>(Wq, Wk, Wv, Ws, bq, bk, bv, bs, Wallt, ball);

    k_init<<<(NNODES + 255) / 256, 256, 0, stream>>>(cnt, S);
    k_count<<<(EEDGES + 255) / 256, 256, 0, stream>>>(dstI, cnt);
    k_dinv<<<(NNODES + 255) / 256, 256, 0, stream>>>(cnt, dinv, cursor);
    k_scan<<<1, 1024, 0, stream>>>(cnt, rowptr);
    k_fill<<<(EEDGES + 255) / 256, 256, 0, stream>>>(srcI, dstI, rowptr, cursor, dinv, srcst, wsort);

    dim3 g1(625, 2);
    k_gemm1<<<g1, 256, 0, stream>>>(x, Wtp, h0bf);

    k_gcn_gather<<<(NNODES * 64 + 255) / 256, 256, 0, stream>>>(rowptr, srcst, wsort, h0bf, dinv, bg, hbf);

    dim3 g2((NNODES + 127) / 128, 4);
    k_gemm2<<<g2, 256, 0, stream>>>(hbf, Wallt, ball, qarr, karr, varr, sarr);

    k_alpha<<<ALPHA_BLOCKS, 256, 0, stream>>>(rowptr, srcst, qarr, karr, alphab, part);
    k_stats<<<1, 1024, 0, stream>>>(part, S);

    k_msg_gather<<<(NNODES * 64 + 255) / 256, 256, 0, stream>>>(rowptr, srcst, varr, sarr, alphab, S, out);
}

// Round 6
// 315.895 us; speedup vs baseline: 1.1596x; 1.1596x over previous
//
#include <hip/hip_runtime.h>
#include <hip/hip_bf16.h>

#define NNODES 20000
#define EEDGES 320000
#define FIN 1024
#define HMID 256
#define DOUT 128
#define ALPHA_BLOCKS ((NNODES + 3) / 4)

typedef __bf16 bf16x8 __attribute__((ext_vector_type(8)));
typedef __bf16 bf16x4 __attribute__((ext_vector_type(4)));
typedef __bf16 bf16x2 __attribute__((ext_vector_type(2)));
typedef float f32x4 __attribute__((ext_vector_type(4)));

typedef const __attribute__((address_space(1))) void* gas_ptr;
typedef __attribute__((address_space(3))) void* las_ptr;
__device__ __forceinline__ void async_copy16(const void* g, void* l) {
    __builtin_amdgcn_global_load_lds((gas_ptr)g, (las_ptr)l, 16, 0, 0);
}

// ---------------- weight packing (vectorized: 16B coalesced writes) ----------------
// Wtp unit addressing identical to before: elem ((kk*2+h)*512 + u)*8 + j holds
// W_gcn[kk*32+(u>>7)*8+j][h*128+(u&127)]. One thread per 16B output unit:
// tid = (kk*2+h)*512 + u (unit index IS tid), 8 column-strided reads (lane-coalesced
// 512B per j across the wave), one bf16x8 store. Old version did 1M scattered 2B
// writes (~32x write amplification).
__global__ void k_pack_w(const float* __restrict__ W, __bf16* __restrict__ Wtp) {
    int tid = blockIdx.x * 256 + threadIdx.x;   // 32768 units
    int kk = tid >> 10;
    int rem = tid & 1023;
    int h = rem >> 9;
    int u = rem & 511;
    int kq = u >> 7, c = u & 127;
    int col = h * 128 + c;
    int k0 = kk * 32 + kq * 8;
    bf16x8 v;
#pragma unroll
    for (int j = 0; j < 8; j++)
        v[j] = (__bf16)W[(size_t)(k0 + j) * HMID + col];
    *(bf16x8*)(Wtp + (size_t)tid * 8) = v;
}

// Wallt[(g*128+n)*256 + k] = W_g[k][n]; one thread per 16B output unit (n, k0u):
// reads 8 row-strided (lane-coalesced 512B per j), writes one bf16x8.
__global__ void k_prep_watt(const float* __restrict__ Wq, const float* __restrict__ Wk,
                            const float* __restrict__ Wv, const float* __restrict__ Ws,
                            const float* __restrict__ bq, const float* __restrict__ bk,
                            const float* __restrict__ bv, const float* __restrict__ bs,
                            __bf16* __restrict__ Wallt, float* __restrict__ ball) {
    int g = blockIdx.y;
    const float* W = (g == 0) ? Wq : (g == 1) ? Wk : (g == 2) ? Wv : Ws;
    int tid = blockIdx.x * 256 + threadIdx.x;   // 4096 units
    int n = tid & 127;
    int k0u = tid >> 7;
    if (k0u < 32) {
        bf16x8 v;
#pragma unroll
        for (int j = 0; j < 8; j++)
            v[j] = (__bf16)W[(size_t)(k0u * 8 + j) * DOUT + n];
        *(bf16x8*)(Wallt + (size_t)(g * DOUT + n) * HMID + k0u * 8) = v;
    }
    if (tid < DOUT) {
        const float* b = (g == 0) ? bq : (g == 1) ? bk : (g == 2) ? bv : bs;
        ball[g * DOUT + tid] = b[tid];
    }
}

// ---------------- CSR build ----------------
__global__ void k_init(int* __restrict__ cnt, float* __restrict__ S) {
    int i = blockIdx.x * 256 + threadIdx.x;
    if (i < NNODES) cnt[i] = 0;
    if (i < 16) S[i] = 0.0f;
}

__global__ void k_count(const int* __restrict__ dst, int* __restrict__ cnt) {
    int e = blockIdx.x * 256 + threadIdx.x;
    if (e < EEDGES) atomicAdd(&cnt[dst[e]], 1);
}

__global__ void k_dinv(const int* __restrict__ cnt, float* __restrict__ dinv,
                       int* __restrict__ cursor) {
    int i = blockIdx.x * 256 + threadIdx.x;
    if (i < NNODES) {
        dinv[i] = rsqrtf((float)cnt[i] + 1.0f);
        cursor[i] = 0;
    }
}

__global__ __launch_bounds__(1024) void k_scan(const int* __restrict__ cnt,
                                               int* __restrict__ rowptr) {
    __shared__ int sh[1024];
    int t = threadIdx.x;
    int base = t * 20;
    int local[20];
    int sum = 0;
#pragma unroll
    for (int j = 0; j < 20; j++) {
        int i = base + j;
        int v = (i < NNODES) ? cnt[i] : 0;
        local[j] = sum;
        sum += v;
    }
    sh[t] = sum;
    __syncthreads();
    for (int off = 1; off < 1024; off <<= 1) {
        int v = (t >= off) ? sh[t - off] : 0;
        __syncthreads();
        sh[t] += v;
        __syncthreads();
    }
    int prev = (t > 0) ? sh[t - 1] : 0;
#pragma unroll
    for (int j = 0; j < 20; j++) {
        int i = base + j;
        if (i < NNODES) rowptr[i] = prev + local[j];
    }
    if (t == 1023) rowptr[NNODES] = sh[1023];
}

__global__ void k_fill(const int* __restrict__ src, const int* __restrict__ dst,
                       const int* __restrict__ rowptr, int* __restrict__ cursor,
                       const float* __restrict__ dinv,
                       int* __restrict__ srcsorted, float* __restrict__ wsorted) {
    int e = blockIdx.x * 256 + threadIdx.x;
    if (e >= EEDGES) return;
    int d = dst[e];
    int s = src[e];
    int pos = atomicAdd(&cursor[d], 1);
    int w = rowptr[d] + pos;
    srcsorted[w] = s;
    wsorted[w] = dinv[s];
}

// ---------------- GEMM1: h0bf = bf16(x @ W_gcn) ----------------
// Best measured structure (r1, 48.8us): 32x128 tile, BK=32, grid (625,2), LDS 10KB,
// ~4.9 blocks/CU. Ledger: 64x128=60, 32x128=48.8, 16x128/BK64=60.4, triple-buf
// counted-vmcnt=59, LDS-free reg-ping/pong=90.9. Do not re-derive; this is the
// empirical optimum of the family.
__global__ __launch_bounds__(256) void k_gemm1(const float* __restrict__ x,
                                               const __bf16* __restrict__ Wtp,
                                               __bf16* __restrict__ h0bf) {
    __shared__ __bf16 As[1024];   // 2 KB: 32 rows x 32 k
    __shared__ __bf16 Bs[4096];   // 8 KB: unit u = kq*128 + c
    int t = threadIdx.x;
    int lane = t & 63;
    int m = lane & 15, q = lane >> 4;
    int w = t >> 6;
    int wc = w * 32;              // wave owns 32 cols, all 32 rows
    int r0 = blockIdx.x * 32;
    int h = blockIdx.y;
    int c0 = h * 128;

    int arow = t >> 3;
    const float* ap = x + (size_t)(r0 + arow) * FIN + (t & 7) * 4;
    __bf16* awr = &As[arow * 32 + ((t & 7) >> 1) * 8 + (t & 1) * 4];
    const __bf16* bb = Wtp + (size_t)h * 4096;

    f32x4 acc[2][2] = {};

    float4 a = *(const float4*)(ap);

#pragma unroll 1
    for (int kk = 0; kk < 32; kk++) {
        async_copy16(bb + (size_t)kk * 8192 + t * 8, &Bs[t * 8]);
        async_copy16(bb + (size_t)kk * 8192 + (t + 256) * 8, &Bs[(t + 256) * 8]);
        bf16x4 av;
        av[0] = (__bf16)a.x; av[1] = (__bf16)a.y; av[2] = (__bf16)a.z; av[3] = (__bf16)a.w;
        *(bf16x4*)awr = av;
        if (kk + 1 < 32) a = *(const float4*)(ap + (kk + 1) * 32);
        __syncthreads();

        bf16x8 af[2], bfr[2];
#pragma unroll
        for (int i = 0; i < 2; i++)
            af[i] = *(const bf16x8*)&As[(i * 16 + m) * 32 + q * 8];
#pragma unroll
        for (int jb = 0; jb < 2; jb++)
            bfr[jb] = *(const bf16x8*)&Bs[(q * 128 + wc + jb * 16 + m) * 8];
#pragma unroll
        for (int i = 0; i < 2; i++)
#pragma unroll
            for (int jb = 0; jb < 2; jb++)
                acc[i][jb] = __builtin_amdgcn_mfma_f32_16x16x32_bf16(af[i], bfr[jb], acc[i][jb], 0, 0, 0);
        __syncthreads();
    }

#pragma unroll
    for (int i = 0; i < 2; i++)
#pragma unroll
        for (int jb = 0; jb < 2; jb++)
#pragma unroll
            for (int r = 0; r < 4; r++) {
                int row = r0 + i * 16 + q * 4 + r;
                int col = c0 + wc + jb * 16 + m;
                h0bf[(size_t)row * 256 + col] = (__bf16)acc[i][jb][r];
            }
}

// ---------------- GCN gather (batch-4 MLP) ----------------
__global__ __launch_bounds__(256) void k_gcn_gather(const int* __restrict__ rowptr,
                                                    const int* __restrict__ srcsorted,
                                                    const float* __restrict__ wsorted,
                                                    const __bf16* __restrict__ h0bf,
                                                    const float* __restrict__ dinv,
                                                    const float* __restrict__ bgcn,
                                                    __bf16* __restrict__ hbf) {
    int gid = blockIdx.x * 256 + threadIdx.x;
    int n = gid >> 6, l = gid & 63;
    if (n >= NNODES) return;
    float dn = dinv[n];
    float wn = dn * dn;
    bf16x4 hv = *(const bf16x4*)(h0bf + (size_t)n * 256 + l * 4);
    float4 b = ((const float4*)bgcn)[l];
    float ax = (float)hv[0] * wn + b.x;
    float ay = (float)hv[1] * wn + b.y;
    float az = (float)hv[2] * wn + b.z;
    float aw = (float)hv[3] * wn + b.w;
    int beg = rowptr[n], end = rowptr[n + 1];
    for (int i = beg; i < end; i += 4) {
        int i1 = i + 1 < end ? i + 1 : end - 1;
        int i2 = i + 2 < end ? i + 2 : end - 1;
        int i3 = i + 3 < end ? i + 3 : end - 1;
        int s0 = srcsorted[i], s1 = srcsorted[i1], s2 = srcsorted[i2], s3 = srcsorted[i3];
        float w0 = wsorted[i] * dn;
        float w1 = (i + 1 < end) ? wsorted[i1] * dn : 0.f;
        float w2 = (i + 2 < end) ? wsorted[i2] * dn : 0.f;
        float w3 = (i + 3 < end) ? wsorted[i3] * dn : 0.f;
        bf16x4 v0 = *(const bf16x4*)(h0bf + (size_t)s0 * 256 + l * 4);
        bf16x4 v1 = *(const bf16x4*)(h0bf + (size_t)s1 * 256 + l * 4);
        bf16x4 v2 = *(const bf16x4*)(h0bf + (size_t)s2 * 256 + l * 4);
        bf16x4 v3 = *(const bf16x4*)(h0bf + (size_t)s3 * 256 + l * 4);
        ax += (float)v0[0] * w0 + (float)v1[0] * w1 + (float)v2[0] * w2 + (float)v3[0] * w3;
        ay += (float)v0[1] * w0 + (float)v1[1] * w1 + (float)v2[1] * w2 + (float)v3[1] * w3;
        az += (float)v0[2] * w0 + (float)v1[2] * w1 + (float)v2[2] * w2 + (float)v3[2] * w3;
        aw += (float)v0[3] * w0 + (float)v1[3] * w1 + (float)v2[3] * w2 + (float)v3[3] * w3;
    }
    bf16x4 o;
    o[0] = (__bf16)(ax >= 0.f ? ax : 0.01f * ax);
    o[1] = (__bf16)(ay >= 0.f ? ay : 0.01f * ay);
    o[2] = (__bf16)(az >= 0.f ? az : 0.01f * az);
    o[3] = (__bf16)(aw >= 0.f ? aw : 0.01f * aw);
    *(bf16x4*)(hbf + (size_t)n * 256 + l * 4) = o;
}

// ---------------- GEMM2 ----------------
__global__ __launch_bounds__(256) void k_gemm2(const __bf16* __restrict__ hbf,
                                               const __bf16* __restrict__ Wallt,
                                               const float* __restrict__ ball,
                                               __bf16* __restrict__ qarr,
                                               __bf16* __restrict__ karr,
                                               __bf16* __restrict__ varr,
                                               __bf16* __restrict__ sarr) {
    __shared__ __bf16 As[4096];
    __shared__ __bf16 Bs[4096];
    int t = threadIdx.x;
    int lane = t & 63;
    int m = lane & 15, q = lane >> 4;
    int wave = t >> 6;
    int wr = (wave & 1) * 64;
    int wc = (wave >> 1) * 64;
    int r0 = blockIdx.x * 128;
    int c0 = blockIdx.y * 128;
    __bf16* tbl = (blockIdx.y == 0) ? qarr : (blockIdx.y == 1) ? karr
                : (blockIdx.y == 2) ? varr : sarr;

    const __bf16* asrc[2];
    __bf16* aldst[2];
#pragma unroll
    for (int j = 0; j < 2; j++) {
        int u = j * 256 + t;
        int row = r0 + (u & 127);
        if (row >= NNODES) row = NNODES - 1;
        asrc[j] = hbf + (size_t)row * HMID + (u >> 7) * 8;
        aldst[j] = &As[(size_t)u * 8];
    }
    const __bf16* bsrc[2];
    __bf16* bldst[2];
#pragma unroll
    for (int j = 0; j < 2; j++) {
        int u = j * 256 + t;
        bsrc[j] = Wallt + (size_t)(c0 + (u & 127)) * HMID + (u >> 7) * 8;
        bldst[j] = &Bs[(size_t)u * 8];
    }

    f32x4 acc[4][4] = {};

    for (int k0 = 0; k0 < HMID; k0 += 32) {
#pragma unroll
        for (int j = 0; j < 2; j++) async_copy16(asrc[j] + k0, aldst[j]);
#pragma unroll
        for (int j = 0; j < 2; j++) async_copy16(bsrc[j] + k0, bldst[j]);
        __syncthreads();

        bf16x8 af[4], bfr[4];
#pragma unroll
        for (int i = 0; i < 4; i++) af[i] = *(const bf16x8*)&As[(size_t)(q * 128 + wr + i * 16 + m) * 8];
#pragma unroll
        for (int jb = 0; jb < 4; jb++) bfr[jb] = *(const bf16x8*)&Bs[(size_t)(q * 128 + wc + jb * 16 + m) * 8];
#pragma unroll
        for (int i = 0; i < 4; i++)
#pragma unroll
            for (int jb = 0; jb < 4; jb++)
                acc[i][jb] = __builtin_amdgcn_mfma_f32_16x16x32_bf16(af[i], bfr[jb], acc[i][jb], 0, 0, 0);
        __syncthreads();
    }

#pragma unroll
    for (int jb = 0; jb < 4; jb++) {
        int dcol = wc + jb * 16 + m;
        float bias = ball[c0 + dcol];
#pragma unroll
        for (int i = 0; i < 4; i++)
#pragma unroll
            for (int r = 0; r < 4; r++) {
                int row = r0 + wr + i * 16 + q * 4 + r;
                if (row < NNODES) tbl[(size_t)row * 128 + dcol] = (__bf16)(acc[i][jb][r] + bias);
            }
    }
}

// ---------------- attention scores ----------------
__global__ __launch_bounds__(256) void k_alpha(const int* __restrict__ rowptr,
                                               const int* __restrict__ srcsorted,
                                               const __bf16* __restrict__ qarr,
                                               const __bf16* __restrict__ karr,
                                               float* __restrict__ alpha,
                                               float* __restrict__ part) {
    int n = (blockIdx.x * 256 + threadIdx.x) >> 6;
    int lane = threadIdx.x & 63;
    int g = lane >> 4, l = lane & 15;
    float s1 = 0.f, s2 = 0.f;
    if (n < NNODES) {
        bf16x8 qb = *(const bf16x8*)(qarr + (size_t)n * 128 + l * 8);
        float qf[8];
#pragma unroll
        for (int j = 0; j < 8; j++) qf[j] = (float)qb[j];
        int beg = rowptr[n], end = rowptr[n + 1];
        for (int i = beg + g; i < end; i += 16) {
            int i1 = i + 4 < end ? i + 4 : end - 1;
            int i2 = i + 8 < end ? i + 8 : end - 1;
            int i3 = i + 12 < end ? i + 12 : end - 1;
            int s0 = srcsorted[i], sA = srcsorted[i1], sB = srcsorted[i2], sC = srcsorted[i3];
            bf16x8 k0 = *(const bf16x8*)(karr + (size_t)s0 * 128 + l * 8);
            bf16x8 k1 = *(const bf16x8*)(karr + (size_t)sA * 128 + l * 8);
            bf16x8 k2 = *(const bf16x8*)(karr + (size_t)sB * 128 + l * 8);
            bf16x8 k3 = *(const bf16x8*)(karr + (size_t)sC * 128 + l * 8);
            float d0 = 0.f, d1 = 0.f, d2 = 0.f, d3 = 0.f;
#pragma unroll
            for (int j = 0; j < 8; j++) {
                d0 += qf[j] * (float)k0[j];
                d1 += qf[j] * (float)k1[j];
                d2 += qf[j] * (float)k2[j];
                d3 += qf[j] * (float)k3[j];
            }
#pragma unroll
            for (int off = 1; off < 16; off <<= 1) {
                d0 += __shfl_xor(d0, off, 64);
                d1 += __shfl_xor(d1, off, 64);
                d2 += __shfl_xor(d2, off, 64);
                d3 += __shfl_xor(d3, off, 64);
            }
            if (l == 0) {
                const float sc = 0.08838834764831845f;
                float a0 = d0 * sc;
                alpha[i] = a0; s1 += a0; s2 += a0 * a0;
                if (i + 4 < end)  { float a = d1 * sc; alpha[i + 4]  = a; s1 += a; s2 += a * a; }
                if (i + 8 < end)  { float a = d2 * sc; alpha[i + 8]  = a; s1 += a; s2 += a * a; }
                if (i + 12 < end) { float a = d3 * sc; alpha[i + 12] = a; s1 += a; s2 += a * a; }
            }
        }
    }
#pragma unroll
    for (int off = 1; off < 64; off <<= 1) {
        s1 += __shfl_xor(s1, off, 64);
        s2 += __shfl_xor(s2, off, 64);
    }
    __shared__ float sh[8];
    int wave = threadIdx.x >> 6;
    if ((threadIdx.x & 63) == 0) { sh[wave] = s1; sh[4 + wave] = s2; }
    __syncthreads();
    if (threadIdx.x == 0) {
        part[2 * blockIdx.x]     = sh[0] + sh[1] + sh[2] + sh[3];
        part[2 * blockIdx.x + 1] = sh[4] + sh[5] + sh[6] + sh[7];
    }
}

__global__ __launch_bounds__(1024) void k_stats(const float* __restrict__ part,
                                                float* __restrict__ S) {
    float s1 = 0.f, s2 = 0.f;
    for (int i = threadIdx.x; i < ALPHA_BLOCKS; i += 1024) {
        s1 += part[2 * i];
        s2 += part[2 * i + 1];
    }
#pragma unroll
    for (int off = 1; off < 64; off <<= 1) {
        s1 += __shfl_xor(s1, off, 64);
        s2 += __shfl_xor(s2, off, 64);
    }
    __shared__ float sh1[16], sh2[16];
    int wave = threadIdx.x >> 6;
    if ((threadIdx.x & 63) == 0) { sh1[wave] = s1; sh2[wave] = s2; }
    __syncthreads();
    if (threadIdx.x == 0) {
        float t1 = 0.f, t2 = 0.f;
#pragma unroll
        for (int w = 0; w < 16; w++) { t1 += sh1[w]; t2 += sh2[w]; }
        float mean = t1 / (float)EEDGES;
        float var = (t2 - (float)EEDGES * mean * mean) / (float)(EEDGES - 1);
        float stdv = sqrtf(fmaxf(var, 1e-20f));
        S[2] = mean;
        S[3] = 3.0f / stdv;
    }
}

// ---------------- output gather ----------------
__global__ __launch_bounds__(256) void k_msg_gather(const int* __restrict__ rowptr,
                                                    const int* __restrict__ srcsorted,
                                                    const __bf16* __restrict__ varr,
                                                    const __bf16* __restrict__ sarr,
                                                    const float* __restrict__ alpha,
                                                    const float* __restrict__ S,
                                                    float* __restrict__ out) {
    int n = (blockIdx.x * 256 + threadIdx.x) >> 6;
    int l = threadIdx.x & 63;
    if (n >= NNODES) return;
    float mean = S[2], scl = S[3];
    bf16x2 sb = *(const bf16x2*)(sarr + (size_t)n * 128 + l * 2);
    float ax = (float)sb[0], ay = (float)sb[1];
    int beg = rowptr[n], end = rowptr[n + 1];
    for (int i = beg; i < end; i += 4) {
        int i1 = i + 1 < end ? i + 1 : end - 1;
        int i2 = i + 2 < end ? i + 2 : end - 1;
        int i3 = i + 3 < end ? i + 3 : end - 1;
        int s0 = srcsorted[i], s1 = srcsorted[i1], s2 = srcsorted[i2], s3 = srcsorted[i3];
        float z0 = (alpha[i] - mean) * scl;
        float z1 = (alpha[i1] - mean) * scl;
        float z2 = (alpha[i2] - mean) * scl;
        float z3 = (alpha[i3] - mean) * scl;
        float g0 = 1.0f / (1.0f + __expf(-z0));
        float g1 = (i + 1 < end) ? 1.0f / (1.0f + __expf(-z1)) : 0.f;
        float g2 = (i + 2 < end) ? 1.0f / (1.0f + __expf(-z2)) : 0.f;
        float g3 = (i + 3 < end) ? 1.0f / (1.0f + __expf(-z3)) : 0.f;
        bf16x2 v0 = *(const bf16x2*)(varr + (size_t)s0 * 128 + l * 2);
        bf16x2 v1 = *(const bf16x2*)(varr + (size_t)s1 * 128 + l * 2);
        bf16x2 v2 = *(const bf16x2*)(varr + (size_t)s2 * 128 + l * 2);
        bf16x2 v3 = *(const bf16x2*)(varr + (size_t)s3 * 128 + l * 2);
        ax += (float)v0[0] * g0 + (float)v1[0] * g1 + (float)v2[0] * g2 + (float)v3[0] * g3;
        ay += (float)v0[1] * g0 + (float)v1[1] * g1 + (float)v2[1] * g2 + (float)v3[1] * g3;
    }
    float2 o; o.x = ax; o.y = ay;
    ((float2*)(out + (size_t)n * DOUT))[l] = o;
}

// ---------------- launch ----------------
extern "C" void kernel_launch(void* const* d_in, const int* in_sizes, int n_in,
                              void* d_out, int out_size, void* d_ws, size_t ws_size,
                              hipStream_t stream) {
    const float* x  = (const float*)d_in[0];
    const int* ei   = (const int*)d_in[1];
    const int* srcI = ei;
    const int* dstI = ei + EEDGES;
    const float* Wg = (const float*)d_in[2];
    const float* bg = (const float*)d_in[3];
    const float* Wq = (const float*)d_in[4];  const float* bq = (const float*)d_in[5];
    const float* Wk = (const float*)d_in[6];  const float* bk = (const float*)d_in[7];
    const float* Wv = (const float*)d_in[8];  const float* bv = (const float*)d_in[9];
    const float* Ws = (const float*)d_in[10]; const float* bs = (const float*)d_in[11];
    float* out = (float*)d_out;

    char* wsb = (char*)d_ws;
    size_t off = 0;
    auto alloc = [&](size_t bytes) -> void* {
        void* p = wsb + off;
        off += (bytes + 255) & ~(size_t)255;
        return p;
    };
    int*    cnt    = (int*)alloc((size_t)NNODES * 4);
    int*    rowptr = (int*)alloc((size_t)(NNODES + 1) * 4);
    int*    cursor = (int*)alloc((size_t)NNODES * 4);
    int*    srcst  = (int*)alloc((size_t)EEDGES * 4);
    float*  wsort  = (float*)alloc((size_t)EEDGES * 4);
    float*  dinv   = (float*)alloc((size_t)NNODES * 4);
    float*  S      = (float*)alloc(64);
    float*  part   = (float*)alloc((size_t)ALPHA_BLOCKS * 2 * 4);
    __bf16* Wtp    = (__bf16*)alloc((size_t)32 * 8192 * 2);
    __bf16* Wallt  = (__bf16*)alloc((size_t)512 * HMID * 2);
    float*  ball   = (float*)alloc(512 * 4);
    __bf16* h0bf   = (__bf16*)alloc((size_t)NNODES * HMID * 2);
    __bf16* hbf    = (__bf16*)alloc((size_t)NNODES * HMID * 2);
    __bf16* qarr   = (__bf16*)alloc((size_t)NNODES * 128 * 2);
    __bf16* karr   = (__bf16*)alloc((size_t)NNODES * 128 * 2);
    __bf16* varr   = (__bf16*)alloc((size_t)NNODES * 128 * 2);
    __bf16* sarr   = (__bf16*)alloc((size_t)NNODES * 128 * 2);
    float*  alphab = (float*)alloc((size_t)EEDGES * 4);
    if (off > ws_size) return;

    k_pack_w<<<128, 256, 0, stream>>>(Wg, Wtp);
    dim3 gw(16, 4);
    k_prep_watt<<<gw, 256, 0, stream>>>(Wq, Wk, Wv, Ws, bq, bk, bv, bs, Wallt, ball);

    k_init<<<(NNODES + 255) / 256, 256, 0, stream>>>(cnt, S);
    k_count<<<(EEDGES + 255) / 256, 256, 0, stream>>>(dstI, cnt);
    k_dinv<<<(NNODES + 255) / 256, 256, 0, stream>>>(cnt, dinv, cursor);
    k_scan<<<1, 1024, 0, stream>>>(cnt, rowptr);
    k_fill<<<(EEDGES + 255) / 256, 256, 0, stream>>>(srcI, dstI, rowptr, cursor, dinv, srcst, wsort);

    dim3 g1(625, 2);
    k_gemm1<<<g1, 256, 0, stream>>>(x, Wtp, h0bf);

    k_gcn_gather<<<(NNODES * 64 + 255) / 256, 256, 0, stream>>>(rowptr, srcst, wsort, h0bf, dinv, bg, hbf);

    dim3 g2((NNODES + 127) / 128, 4);
    k_gemm2<<<g2, 256, 0, stream>>>(hbf, Wallt, ball, qarr, karr, varr, sarr);

    k_alpha<<<ALPHA_BLOCKS, 256, 0, stream>>>(rowptr, srcst, qarr, karr, alphab, part);
    k_stats<<<1, 1024, 0, stream>>>(part, S);

    k_msg_gather<<<(NNODES * 64 + 255) / 256, 256, 0, stream>>>(rowptr, srcst, varr, sarr, alphab, S, out);
}

// Round 7
// 314.476 us; speedup vs baseline: 1.1649x; 1.0045x over previous
//
#include <hip/hip_runtime.h>
#include <hip/hip_bf16.h>

#define NNODES 20000
#define EEDGES 320000
#define FIN 1024
#define HMID 256
#define DOUT 128
#define ALPHA_BLOCKS ((NNODES + 3) / 4)

typedef __bf16 bf16x8 __attribute__((ext_vector_type(8)));
typedef __bf16 bf16x4 __attribute__((ext_vector_type(4)));
typedef __bf16 bf16x2 __attribute__((ext_vector_type(2)));
typedef float f32x4 __attribute__((ext_vector_type(4)));

typedef const __attribute__((address_space(1))) void* gas_ptr;
typedef __attribute__((address_space(3))) void* las_ptr;
__device__ __forceinline__ void async_copy16(const void* g, void* l) {
    __builtin_amdgcn_global_load_lds((gas_ptr)g, (las_ptr)l, 16, 0, 0);
}

__device__ __forceinline__ float readlane_f(float v, int lane) {
    return __uint_as_float(__builtin_amdgcn_readlane(__float_as_uint(v), lane));
}

// ---------------- weight packing (vectorized: 16B coalesced writes) ----------------
__global__ void k_pack_w(const float* __restrict__ W, __bf16* __restrict__ Wtp) {
    int tid = blockIdx.x * 256 + threadIdx.x;   // 32768 units
    int kk = tid >> 10;
    int rem = tid & 1023;
    int h = rem >> 9;
    int u = rem & 511;
    int kq = u >> 7, c = u & 127;
    int col = h * 128 + c;
    int k0 = kk * 32 + kq * 8;
    bf16x8 v;
#pragma unroll
    for (int j = 0; j < 8; j++)
        v[j] = (__bf16)W[(size_t)(k0 + j) * HMID + col];
    *(bf16x8*)(Wtp + (size_t)tid * 8) = v;
}

__global__ void k_prep_watt(const float* __restrict__ Wq, const float* __restrict__ Wk,
                            const float* __restrict__ Wv, const float* __restrict__ Ws,
                            const float* __restrict__ bq, const float* __restrict__ bk,
                            const float* __restrict__ bv, const float* __restrict__ bs,
                            __bf16* __restrict__ Wallt, float* __restrict__ ball) {
    int g = blockIdx.y;
    const float* W = (g == 0) ? Wq : (g == 1) ? Wk : (g == 2) ? Wv : Ws;
    int tid = blockIdx.x * 256 + threadIdx.x;   // 4096 units
    int n = tid & 127;
    int k0u = tid >> 7;
    if (k0u < 32) {
        bf16x8 v;
#pragma unroll
        for (int j = 0; j < 8; j++)
            v[j] = (__bf16)W[(size_t)(k0u * 8 + j) * DOUT + n];
        *(bf16x8*)(Wallt + (size_t)(g * DOUT + n) * HMID + k0u * 8) = v;
    }
    if (tid < DOUT) {
        const float* b = (g == 0) ? bq : (g == 1) ? bk : (g == 2) ? bv : bs;
        ball[g * DOUT + tid] = b[tid];
    }
}

// ---------------- CSR build ----------------
__global__ void k_init(int* __restrict__ cnt, float* __restrict__ S) {
    int i = blockIdx.x * 256 + threadIdx.x;
    if (i < NNODES) cnt[i] = 0;
    if (i < 16) S[i] = 0.0f;
}

__global__ void k_count(const int* __restrict__ dst, int* __restrict__ cnt) {
    int e = blockIdx.x * 256 + threadIdx.x;
    if (e < EEDGES) atomicAdd(&cnt[dst[e]], 1);
}

__global__ void k_dinv(const int* __restrict__ cnt, float* __restrict__ dinv,
                       int* __restrict__ cursor) {
    int i = blockIdx.x * 256 + threadIdx.x;
    if (i < NNODES) {
        dinv[i] = rsqrtf((float)cnt[i] + 1.0f);
        cursor[i] = 0;
    }
}

__global__ __launch_bounds__(1024) void k_scan(const int* __restrict__ cnt,
                                               int* __restrict__ rowptr) {
    __shared__ int sh[1024];
    int t = threadIdx.x;
    int base = t * 20;
    int local[20];
    int sum = 0;
#pragma unroll
    for (int j = 0; j < 20; j++) {
        int i = base + j;
        int v = (i < NNODES) ? cnt[i] : 0;
        local[j] = sum;
        sum += v;
    }
    sh[t] = sum;
    __syncthreads();
    for (int off = 1; off < 1024; off <<= 1) {
        int v = (t >= off) ? sh[t - off] : 0;
        __syncthreads();
        sh[t] += v;
        __syncthreads();
    }
    int prev = (t > 0) ? sh[t - 1] : 0;
#pragma unroll
    for (int j = 0; j < 20; j++) {
        int i = base + j;
        if (i < NNODES) rowptr[i] = prev + local[j];
    }
    if (t == 1023) rowptr[NNODES] = sh[1023];
}

__global__ void k_fill(const int* __restrict__ src, const int* __restrict__ dst,
                       const int* __restrict__ rowptr, int* __restrict__ cursor,
                       const float* __restrict__ dinv,
                       int* __restrict__ srcsorted, float* __restrict__ wsorted) {
    int e = blockIdx.x * 256 + threadIdx.x;
    if (e >= EEDGES) return;
    int d = dst[e];
    int s = src[e];
    int pos = atomicAdd(&cursor[d], 1);
    int w = rowptr[d] + pos;
    srcsorted[w] = s;
    wsorted[w] = dinv[s];
}

// ---------------- GEMM1: h0bf = bf16(x @ W_gcn) ----------------
// Best measured structure (r1, 48.8us). Ledger: 64x128=60, 32x128=48.8,
// 16x128/BK64=60.4, triple-buf counted-vmcnt=59, LDS-free=90.9. Do not re-derive.
__global__ __launch_bounds__(256) void k_gemm1(const float* __restrict__ x,
                                               const __bf16* __restrict__ Wtp,
                                               __bf16* __restrict__ h0bf) {
    __shared__ __bf16 As[1024];   // 2 KB: 32 rows x 32 k
    __shared__ __bf16 Bs[4096];   // 8 KB: unit u = kq*128 + c
    int t = threadIdx.x;
    int lane = t & 63;
    int m = lane & 15, q = lane >> 4;
    int w = t >> 6;
    int wc = w * 32;
    int r0 = blockIdx.x * 32;
    int h = blockIdx.y;
    int c0 = h * 128;

    int arow = t >> 3;
    const float* ap = x + (size_t)(r0 + arow) * FIN + (t & 7) * 4;
    __bf16* awr = &As[arow * 32 + ((t & 7) >> 1) * 8 + (t & 1) * 4];
    const __bf16* bb = Wtp + (size_t)h * 4096;

    f32x4 acc[2][2] = {};

    float4 a = *(const float4*)(ap);

#pragma unroll 1
    for (int kk = 0; kk < 32; kk++) {
        async_copy16(bb + (size_t)kk * 8192 + t * 8, &Bs[t * 8]);
        async_copy16(bb + (size_t)kk * 8192 + (t + 256) * 8, &Bs[(t + 256) * 8]);
        bf16x4 av;
        av[0] = (__bf16)a.x; av[1] = (__bf16)a.y; av[2] = (__bf16)a.z; av[3] = (__bf16)a.w;
        *(bf16x4*)awr = av;
        if (kk + 1 < 32) a = *(const float4*)(ap + (kk + 1) * 32);
        __syncthreads();

        bf16x8 af[2], bfr[2];
#pragma unroll
        for (int i = 0; i < 2; i++)
            af[i] = *(const bf16x8*)&As[(i * 16 + m) * 32 + q * 8];
#pragma unroll
        for (int jb = 0; jb < 2; jb++)
            bfr[jb] = *(const bf16x8*)&Bs[(q * 128 + wc + jb * 16 + m) * 8];
#pragma unroll
        for (int i = 0; i < 2; i++)
#pragma unroll
            for (int jb = 0; jb < 2; jb++)
                acc[i][jb] = __builtin_amdgcn_mfma_f32_16x16x32_bf16(af[i], bfr[jb], acc[i][jb], 0, 0, 0);
        __syncthreads();
    }

#pragma unroll
    for (int i = 0; i < 2; i++)
#pragma unroll
        for (int jb = 0; jb < 2; jb++)
#pragma unroll
            for (int r = 0; r < 4; r++) {
                int row = r0 + i * 16 + q * 4 + r;
                int col = c0 + wc + jb * 16 + m;
                h0bf[(size_t)row * 256 + col] = (__bf16)acc[i][jb][r];
            }
}

// ---------------- GCN gather ----------------
// v2: coalesced index/weight prefetch (lane l holds edge beg+l), readlane broadcast
// (SGPR base, no per-batch index chase), batch-8 row loads, uniform-branch tail.
// Fallback direct loop for deg>64 (P~0 for Poisson(16)).
__global__ __launch_bounds__(256) void k_gcn_gather(const int* __restrict__ rowptr,
                                                    const int* __restrict__ srcsorted,
                                                    const float* __restrict__ wsorted,
                                                    const __bf16* __restrict__ h0bf,
                                                    const float* __restrict__ dinv,
                                                    const float* __restrict__ bgcn,
                                                    __bf16* __restrict__ hbf) {
    int gid = blockIdx.x * 256 + threadIdx.x;
    int n = gid >> 6, l = gid & 63;
    if (n >= NNODES) return;
    float dn = dinv[n];
    float wn = dn * dn;
    bf16x4 hv = *(const bf16x4*)(h0bf + (size_t)n * 256 + l * 4);
    float4 b = ((const float4*)bgcn)[l];
    float ax = (float)hv[0] * wn + b.x;
    float ay = (float)hv[1] * wn + b.y;
    float az = (float)hv[2] * wn + b.z;
    float aw = (float)hv[3] * wn + b.w;
    int beg = rowptr[n], end = rowptr[n + 1];
    int deg = end - beg;
    int degc = deg < 64 ? deg : 64;

    int sidx = 0; float swt = 0.f;
    if (l < degc) {
        sidx = srcsorted[beg + l];
        swt = wsorted[beg + l] * dn;
    }

    for (int e0 = 0; e0 < degc; e0 += 8) {
#pragma unroll
        for (int j = 0; j < 8; j++) {
            int e = e0 + j;
            if (e >= degc) break;                       // wave-uniform
            int s = __builtin_amdgcn_readlane(sidx, e);
            float wv = readlane_f(swt, e);
            bf16x4 v = *(const bf16x4*)(h0bf + (size_t)s * 256 + l * 4);
            ax += (float)v[0] * wv;
            ay += (float)v[1] * wv;
            az += (float)v[2] * wv;
            aw += (float)v[3] * wv;
        }
    }
    for (int i = beg + 64; i < end; i++) {              // rare tail deg>64
        int s = srcsorted[i];
        float wv = wsorted[i] * dn;
        bf16x4 v = *(const bf16x4*)(h0bf + (size_t)s * 256 + l * 4);
        ax += (float)v[0] * wv;
        ay += (float)v[1] * wv;
        az += (float)v[2] * wv;
        aw += (float)v[3] * wv;
    }
    bf16x4 o;
    o[0] = (__bf16)(ax >= 0.f ? ax : 0.01f * ax);
    o[1] = (__bf16)(ay >= 0.f ? ay : 0.01f * ay);
    o[2] = (__bf16)(az >= 0.f ? az : 0.01f * az);
    o[3] = (__bf16)(aw >= 0.f ? aw : 0.01f * aw);
    *(bf16x4*)(hbf + (size_t)n * 256 + l * 4) = o;
}

// ---------------- GEMM2 ----------------
// v2: 64x128 tile, grid (313,4)=1252 blocks -> 4.9 blocks/CU (was 2.45 at 128x128).
// Mirrors the measured r0->r1 gemm1 occupancy win. LDS 12KB.
__global__ __launch_bounds__(256) void k_gemm2(const __bf16* __restrict__ hbf,
                                               const __bf16* __restrict__ Wallt,
                                               const float* __restrict__ ball,
                                               __bf16* __restrict__ qarr,
                                               __bf16* __restrict__ karr,
                                               __bf16* __restrict__ varr,
                                               __bf16* __restrict__ sarr) {
    __shared__ __bf16 As[2048];   // 4 KB: unit u = ku*64 + r
    __shared__ __bf16 Bs[4096];   // 8 KB: unit u = ku*128 + c
    int t = threadIdx.x;
    int lane = t & 63;
    int m = lane & 15, q = lane >> 4;
    int wave = t >> 6;
    int wr = (wave & 1) * 32;
    int wc = (wave >> 1) * 64;
    int r0 = blockIdx.x * 64;
    int c0 = blockIdx.y * 128;
    __bf16* tbl = (blockIdx.y == 0) ? qarr : (blockIdx.y == 1) ? karr
                : (blockIdx.y == 2) ? varr : sarr;

    int arow = r0 + (t & 63);
    if (arow >= NNODES) arow = NNODES - 1;
    const __bf16* asrc = hbf + (size_t)arow * HMID + (t >> 6) * 8;
    __bf16* aldst = &As[(size_t)t * 8];
    int u1 = t + 256;
    const __bf16* bsrc0 = Wallt + (size_t)(c0 + (t & 127)) * HMID + (t >> 7) * 8;
    __bf16* bldst0 = &Bs[(size_t)t * 8];
    const __bf16* bsrc1 = Wallt + (size_t)(c0 + (u1 & 127)) * HMID + (u1 >> 7) * 8;
    __bf16* bldst1 = &Bs[(size_t)u1 * 8];

    f32x4 acc[2][4] = {};

    for (int k0 = 0; k0 < HMID; k0 += 32) {
        async_copy16(asrc + k0, aldst);
        async_copy16(bsrc0 + k0, bldst0);
        async_copy16(bsrc1 + k0, bldst1);
        __syncthreads();

        bf16x8 af[2], bfr[4];
#pragma unroll
        for (int i = 0; i < 2; i++)
            af[i] = *(const bf16x8*)&As[(size_t)(q * 64 + wr + i * 16 + m) * 8];
#pragma unroll
        for (int jb = 0; jb < 4; jb++)
            bfr[jb] = *(const bf16x8*)&Bs[(size_t)(q * 128 + wc + jb * 16 + m) * 8];
#pragma unroll
        for (int i = 0; i < 2; i++)
#pragma unroll
            for (int jb = 0; jb < 4; jb++)
                acc[i][jb] = __builtin_amdgcn_mfma_f32_16x16x32_bf16(af[i], bfr[jb], acc[i][jb], 0, 0, 0);
        __syncthreads();
    }

#pragma unroll
    for (int jb = 0; jb < 4; jb++) {
        int dcol = wc + jb * 16 + m;
        float bias = ball[c0 + dcol];
#pragma unroll
        for (int i = 0; i < 2; i++)
#pragma unroll
            for (int r = 0; r < 4; r++) {
                int row = r0 + wr + i * 16 + q * 4 + r;
                if (row < NNODES) tbl[(size_t)row * 128 + dcol] = (__bf16)(acc[i][jb][r] + bias);
            }
    }
}

// ---------------- attention scores ----------------
__global__ __launch_bounds__(256) void k_alpha(const int* __restrict__ rowptr,
                                               const int* __restrict__ srcsorted,
                                               const __bf16* __restrict__ qarr,
                                               const __bf16* __restrict__ karr,
                                               float* __restrict__ alpha,
                                               float* __restrict__ part) {
    int n = (blockIdx.x * 256 + threadIdx.x) >> 6;
    int lane = threadIdx.x & 63;
    int g = lane >> 4, l = lane & 15;
    float s1 = 0.f, s2 = 0.f;
    if (n < NNODES) {
        bf16x8 qb = *(const bf16x8*)(qarr + (size_t)n * 128 + l * 8);
        float qf[8];
#pragma unroll
        for (int j = 0; j < 8; j++) qf[j] = (float)qb[j];
        int beg = rowptr[n], end = rowptr[n + 1];
        for (int i = beg + g; i < end; i += 16) {
            int i1 = i + 4 < end ? i + 4 : end - 1;
            int i2 = i + 8 < end ? i + 8 : end - 1;
            int i3 = i + 12 < end ? i + 12 : end - 1;
            int s0 = srcsorted[i], sA = srcsorted[i1], sB = srcsorted[i2], sC = srcsorted[i3];
            bf16x8 k0 = *(const bf16x8*)(karr + (size_t)s0 * 128 + l * 8);
            bf16x8 k1 = *(const bf16x8*)(karr + (size_t)sA * 128 + l * 8);
            bf16x8 k2 = *(const bf16x8*)(karr + (size_t)sB * 128 + l * 8);
            bf16x8 k3 = *(const bf16x8*)(karr + (size_t)sC * 128 + l * 8);
            float d0 = 0.f, d1 = 0.f, d2 = 0.f, d3 = 0.f;
#pragma unroll
            for (int j = 0; j < 8; j++) {
                d0 += qf[j] * (float)k0[j];
                d1 += qf[j] * (float)k1[j];
                d2 += qf[j] * (float)k2[j];
                d3 += qf[j] * (float)k3[j];
            }
#pragma unroll
            for (int off = 1; off < 16; off <<= 1) {
                d0 += __shfl_xor(d0, off, 64);
                d1 += __shfl_xor(d1, off, 64);
                d2 += __shfl_xor(d2, off, 64);
                d3 += __shfl_xor(d3, off, 64);
            }
            if (l == 0) {
                const float sc = 0.08838834764831845f;
                float a0 = d0 * sc;
                alpha[i] = a0; s1 += a0; s2 += a0 * a0;
                if (i + 4 < end)  { float a = d1 * sc; alpha[i + 4]  = a; s1 += a; s2 += a * a; }
                if (i + 8 < end)  { float a = d2 * sc; alpha[i + 8]  = a; s1 += a; s2 += a * a; }
                if (i + 12 < end) { float a = d3 * sc; alpha[i + 12] = a; s1 += a; s2 += a * a; }
            }
        }
    }
#pragma unroll
    for (int off = 1; off < 64; off <<= 1) {
        s1 += __shfl_xor(s1, off, 64);
        s2 += __shfl_xor(s2, off, 64);
    }
    __shared__ float sh[8];
    int wave = threadIdx.x >> 6;
    if ((threadIdx.x & 63) == 0) { sh[wave] = s1; sh[4 + wave] = s2; }
    __syncthreads();
    if (threadIdx.x == 0) {
        part[2 * blockIdx.x]     = sh[0] + sh[1] + sh[2] + sh[3];
        part[2 * blockIdx.x + 1] = sh[4] + sh[5] + sh[6] + sh[7];
    }
}

__global__ __launch_bounds__(1024) void k_stats(const float* __restrict__ part,
                                                float* __restrict__ S) {
    float s1 = 0.f, s2 = 0.f;
    for (int i = threadIdx.x; i < ALPHA_BLOCKS; i += 1024) {
        s1 += part[2 * i];
        s2 += part[2 * i + 1];
    }
#pragma unroll
    for (int off = 1; off < 64; off <<= 1) {
        s1 += __shfl_xor(s1, off, 64);
        s2 += __shfl_xor(s2, off, 64);
    }
    __shared__ float sh1[16], sh2[16];
    int wave = threadIdx.x >> 6;
    if ((threadIdx.x & 63) == 0) { sh1[wave] = s1; sh2[wave] = s2; }
    __syncthreads();
    if (threadIdx.x == 0) {
        float t1 = 0.f, t2 = 0.f;
#pragma unroll
        for (int w = 0; w < 16; w++) { t1 += sh1[w]; t2 += sh2[w]; }
        float mean = t1 / (float)EEDGES;
        float var = (t2 - (float)EEDGES * mean * mean) / (float)(EEDGES - 1);
        float stdv = sqrtf(fmaxf(var, 1e-20f));
        S[2] = mean;
        S[3] = 3.0f / stdv;
    }
}

// ---------------- output gather ----------------
// v2: coalesced index+alpha prefetch; each lane computes its OWN edge's sigmoid once
// (was: all 64 lanes redundantly computing expf for every edge). readlane broadcast.
__global__ __launch_bounds__(256) void k_msg_gather(const int* __restrict__ rowptr,
                                                    const int* __restrict__ srcsorted,
                                                    const __bf16* __restrict__ varr,
                                                    const __bf16* __restrict__ sarr,
                                                    const float* __restrict__ alpha,
                                                    const float* __restrict__ S,
                                                    float* __restrict__ out) {
    int n = (blockIdx.x * 256 + threadIdx.x) >> 6;
    int l = threadIdx.x & 63;
    if (n >= NNODES) return;
    float mean = S[2], scl = S[3];
    bf16x2 sb = *(const bf16x2*)(sarr + (size_t)n * 128 + l * 2);
    float ax = (float)sb[0], ay = (float)sb[1];
    int beg = rowptr[n], end = rowptr[n + 1];
    int deg = end - beg;
    int degc = deg < 64 ? deg : 64;

    int sidx = 0; float gate = 0.f;
    if (l < degc) {
        sidx = srcsorted[beg + l];
        float z = (alpha[beg + l] - mean) * scl;
        gate = 1.0f / (1.0f + __expf(-z));
    }

    for (int e0 = 0; e0 < degc; e0 += 8) {
#pragma unroll
        for (int j = 0; j < 8; j++) {
            int e = e0 + j;
            if (e >= degc) break;                       // wave-uniform
            int s = __builtin_amdgcn_readlane(sidx, e);
            float gv = readlane_f(gate, e);
            bf16x2 v = *(const bf16x2*)(varr + (size_t)s * 128 + l * 2);
            ax += (float)v[0] * gv;
            ay += (float)v[1] * gv;
        }
    }
    for (int i = beg + 64; i < end; i++) {              // rare tail deg>64
        int s = srcsorted[i];
        float z = (alpha[i] - mean) * scl;
        float gv = 1.0f / (1.0f + __expf(-z));
        bf16x2 v = *(const bf16x2*)(varr + (size_t)s * 128 + l * 2);
        ax += (float)v[0] * gv;
        ay += (float)v[1] * gv;
    }
    float2 o; o.x = ax; o.y = ay;
    ((float2*)(out + (size_t)n * DOUT))[l] = o;
}

// ---------------- launch ----------------
extern "C" void kernel_launch(void* const* d_in, const int* in_sizes, int n_in,
                              void* d_out, int out_size, void* d_ws, size_t ws_size,
                              hipStream_t stream) {
    const float* x  = (const float*)d_in[0];
    const int* ei   = (const int*)d_in[1];
    const int* srcI = ei;
    const int* dstI = ei + EEDGES;
    const float* Wg = (const float*)d_in[2];
    const float* bg = (const float*)d_in[3];
    const float* Wq = (const float*)d_in[4];  const float* bq = (const float*)d_in[5];
    const float* Wk = (const float*)d_in[6];  const float* bk = (const float*)d_in[7];
    const float* Wv = (const float*)d_in[8];  const float* bv = (const float*)d_in[9];
    const float* Ws = (const float*)d_in[10]; const float* bs = (const float*)d_in[11];
    float* out = (float*)d_out;

    char* wsb = (char*)d_ws;
    size_t off = 0;
    auto alloc = [&](size_t bytes) -> void* {
        void* p = wsb + off;
        off += (bytes + 255) & ~(size_t)255;
        return p;
    };
    int*    cnt    = (int*)alloc((size_t)NNODES * 4);
    int*    rowptr = (int*)alloc((size_t)(NNODES + 1) * 4);
    int*    cursor = (int*)alloc((size_t)NNODES * 4);
    int*    srcst  = (int*)alloc((size_t)EEDGES * 4);
    float*  wsort  = (float*)alloc((size_t)EEDGES * 4);
    float*  dinv   = (float*)alloc((size_t)NNODES * 4);
    float*  S      = (float*)alloc(64);
    float*  part   = (float*)alloc((size_t)ALPHA_BLOCKS * 2 * 4);
    __bf16* Wtp    = (__bf16*)alloc((size_t)32 * 8192 * 2);
    __bf16* Wallt  = (__bf16*)alloc((size_t)512 * HMID * 2);
    float*  ball   = (float*)alloc(512 * 4);
    __bf16* h0bf   = (__bf16*)alloc((size_t)NNODES * HMID * 2);
    __bf16* hbf    = (__bf16*)alloc((size_t)NNODES * HMID * 2);
    __bf16* qarr   = (__bf16*)alloc((size_t)NNODES * 128 * 2);
    __bf16* karr   = (__bf16*)alloc((size_t)NNODES * 128 * 2);
    __bf16* varr   = (__bf16*)alloc((size_t)NNODES * 128 * 2);
    __bf16* sarr   = (__bf16*)alloc((size_t)NNODES * 128 * 2);
    float*  alphab = (float*)alloc((size_t)EEDGES * 4);
    if (off > ws_size) return;

    k_pack_w<<<128, 256, 0, stream>>>(Wg, Wtp);
    dim3 gw(16, 4);
    k_prep_watt<<<gw, 256, 0, stream>>>(Wq, Wk, Wv, Ws, bq, bk, bv, bs, Wallt, ball);

    k_init<<<(NNODES + 255) / 256, 256, 0, stream>>>(cnt, S);
    k_count<<<(EEDGES + 255) / 256, 256, 0, stream>>>(dstI, cnt);
    k_dinv<<<(NNODES + 255) / 256, 256, 0, stream>>>(cnt, dinv, cursor);
    k_scan<<<1, 1024, 0, stream>>>(cnt, rowptr);
    k_fill<<<(EEDGES + 255) / 256, 256, 0, stream>>>(srcI, dstI, rowptr, cursor, dinv, srcst, wsort);

    dim3 g1(625, 2);
    k_gemm1<<<g1, 256, 0, stream>>>(x, Wtp, h0bf);

    k_gcn_gather<<<(NNODES * 64 + 255) / 256, 256, 0, stream>>>(rowptr, srcst, wsort, h0bf, dinv, bg, hbf);

    dim3 g2(313, 4);
    k_gemm2<<<g2, 256, 0, stream>>>(hbf, Wallt, ball, qarr, karr, varr, sarr);

    k_alpha<<<ALPHA_BLOCKS, 256, 0, stream>>>(rowptr, srcst, qarr, karr, alphab, part);
    k_stats<<<1, 1024, 0, stream>>>(part, S);

    k_msg_gather<<<(NNODES * 64 + 255) / 256, 256, 0, stream>>>(rowptr, srcst, varr, sarr, alphab, S, out);
}